// Round 4
// baseline (190.290 us; speedup 1.0000x reference)
//
#include <hip/hip_runtime.h>

#define B_ 4
#define T_ 2048
#define C_ 1024
#define D_ 128
#define LOG2E 1.4426950408889634f
#define QSCALE 0.08838834764831845f  // 128^-0.5

typedef float f32x4 __attribute__((ext_vector_type(4)));
typedef short s16x8 __attribute__((ext_vector_type(8)));
typedef unsigned short u16;

__device__ __forceinline__ u16 f2bf(float x){
  unsigned u = __builtin_bit_cast(unsigned, x);
  u += 0x7FFFu + ((u >> 16) & 1u);   // RNE
  return (u16)(u >> 16);
}
__device__ __forceinline__ float bf2f(u16 h){
  unsigned u = ((unsigned)h) << 16;
  return __builtin_bit_cast(float, u);
}

static __device__ __forceinline__ f32x4 mfma16(s16x8 a, s16x8 b, f32x4 c){
  return __builtin_amdgcn_mfma_f32_16x16x32_bf16(a, b, c, 0, 0, 0);
}

#define GL16(gp, lp) __builtin_amdgcn_global_load_lds( \
    (const __attribute__((address_space(1))) void*)(gp), \
    (__attribute__((address_space(3))) void*)(lp), 16, 0, 0)

// ---- kernel 1: fused prep. blocks [0,4096): x fp32 -> hi/lo bf16.
//      blocks [4096,4192): W (C,D) x3 -> W^T [384][1024] hi/lo (LDS transpose).
__global__ __launch_bounds__(256) void prep_kernel(
    const float* __restrict__ x,
    const float* __restrict__ Wq, const float* __restrict__ Wk,
    const float* __restrict__ Wv,
    u16* __restrict__ xh, u16* __restrict__ xl,
    u16* __restrict__ wth, u16* __restrict__ wtl){
  __shared__ float tile[64][65];
  int bidx = blockIdx.x;
  if (bidx < 4096){
    size_t i = ((size_t)bidx * 256 + threadIdx.x) * 8;
    float4 a = *(const float4*)(x + i);
    float4 b = *(const float4*)(x + i + 4);
    float v[8] = {a.x, a.y, a.z, a.w, b.x, b.y, b.z, b.w};
    s16x8 vh, vl;
#pragma unroll
    for (int j = 0; j < 8; ++j){
      u16 h = f2bf(v[j]);
      vh[j] = (short)h;
      vl[j] = (short)f2bf(v[j] - bf2f(h));
    }
    *(s16x8*)(xh + i) = vh;
    *(s16x8*)(xl + i) = vl;
  } else {
    int blk = bidx - 4096;           // 96 = 3 * 16 * 2
    int w = blk >> 5; int rem = blk & 31;
    int k0 = (rem >> 1) * 64, d0 = (rem & 1) * 64;
    const float* W = (w == 0) ? Wq : ((w == 1) ? Wk : Wv);
    int t = threadIdx.x;
#pragma unroll
    for (int i = 0; i < 16; ++i){
      int idx = t + i * 256;
      int kk = idx >> 6, dd = idx & 63;
      tile[kk][dd] = W[(size_t)(k0 + kk) * 128 + d0 + dd];
    }
    __syncthreads();
#pragma unroll
    for (int i = 0; i < 16; ++i){
      int idx = t + i * 256;
      int dd = idx >> 6, kk = idx & 63;
      float v = tile[kk][dd];
      u16 h = f2bf(v);
      u16 lo = f2bf(v - bf2f(h));
      size_t o = (size_t)(w * 128 + d0 + dd) * 1024 + k0 + kk;
      wth[o] = h; wtl[o] = lo;
    }
  }
}

// ------- kernel 2: QKV GEMM, hi/lo bf16, 64x64 tile, BK=64, 4 waves -------
// 768 blocks = exactly 3 resident blocks per CU (32 KB LDS each), balanced.
// XCD-clustered, ty-fastest: per XCD, the 6 blocks sharing one A-band
// (m-band, 256 KB hi+lo) are temporally adjacent -> A re-reads are L2 hits
// instead of thrashing (round-3 mapping cycled 16 bands = 4 MB between
// reuses, exactly the per-XCD L2 size). W^T (3 MB hi+lo) stays L2-resident.
__global__ __launch_bounds__(256) void qkv_gemm_kernel(
    const u16* __restrict__ xh, const u16* __restrict__ xl,
    const u16* __restrict__ wth, const u16* __restrict__ wtl,
    u16* __restrict__ qh, u16* __restrict__ ql,
    u16* __restrict__ kh, u16* __restrict__ kl,
    u16* __restrict__ vth, u16* __restrict__ vtl){
  __shared__ u16 Ah[64 * 64], Al[64 * 64], Bh[64 * 64], Bl[64 * 64];
  int bid = blockIdx.x;              // 768
  int xcd = bid & 7, s = bid >> 3;   // s in [0,96)
  int mband = s / 6;                 // 0..15  (A-band within this XCD's set)
  int ty = s - mband * 6;            // 0..5   (fastest -> L2 A-reuse)
  int mx = (xcd << 4) | mband;       // 0..127, bijective
  int m0 = mx * 64;
  int n0 = ty * 64;
  int t = threadIdx.x;
  int lane = t & 63, wv = t >> 6;
  int c = lane & 15, g = lane >> 4;
  int wm = (wv >> 1) * 32, wn = (wv & 1) * 32;
  f32x4 acc[2][2] = {};

  for (int kt = 0; kt < 16; ++kt){
    int k0 = kt * 64;
    __syncthreads();
#pragma unroll
    for (int i = 0; i < 2; ++i){
      int L0 = i * 256 + wv * 64;
      int L = L0 + lane;
      int row = L >> 3, ch = (L & 7) * 8;
      size_t goA = (size_t)(m0 + row) * 1024 + k0 + ch;
      size_t goB = (size_t)(n0 + row) * 1024 + k0 + ch;
      GL16(xh + goA, &Ah[L0 * 8]);
      GL16(xl + goA, &Al[L0 * 8]);
      GL16(wth + goB, &Bh[L0 * 8]);
      GL16(wtl + goB, &Bl[L0 * 8]);
    }
    __syncthreads();
#pragma unroll
    for (int ks = 0; ks < 2; ++ks){
      s16x8 af_h[2], af_l[2], bf_h[2], bf_l[2];
#pragma unroll
      for (int mf = 0; mf < 2; ++mf){
        int off = (wm + mf * 16 + c) * 64 + ks * 32 + g * 8;
        af_h[mf] = *(const s16x8*)&Ah[off];
        af_l[mf] = *(const s16x8*)&Al[off];
      }
#pragma unroll
      for (int nf = 0; nf < 2; ++nf){
        int off = (wn + nf * 16 + c) * 64 + ks * 32 + g * 8;
        bf_h[nf] = *(const s16x8*)&Bh[off];
        bf_l[nf] = *(const s16x8*)&Bl[off];
      }
#pragma unroll
      for (int mf = 0; mf < 2; ++mf)
#pragma unroll
        for (int nf = 0; nf < 2; ++nf){
          acc[mf][nf] = mfma16(af_h[mf], bf_h[nf], acc[mf][nf]);
          acc[mf][nf] = mfma16(af_h[mf], bf_l[nf], acc[mf][nf]);
          acc[mf][nf] = mfma16(af_l[mf], bf_h[nf], acc[mf][nf]);
        }
    }
  }

  int tile_n = ty;
#pragma unroll
  for (int mf = 0; mf < 2; ++mf)
#pragma unroll
    for (int nf = 0; nf < 2; ++nf){
      int n_g = n0 + wn + nf * 16 + c;
      int m_base = m0 + wm + mf * 16 + g * 4;
      if (tile_n < 4){
        float sc = (tile_n < 2) ? QSCALE : 1.0f;
        u16* oh = (tile_n < 2) ? qh : kh;
        u16* ol = (tile_n < 2) ? ql : kl;
        int d = n_g & 127;
#pragma unroll
        for (int r = 0; r < 4; ++r){
          float v = acc[mf][nf][r] * sc;
          u16 h = f2bf(v);
          u16 lo = f2bf(v - bf2f(h));
          size_t o = (size_t)(m_base + r) * 128 + d;
          oh[o] = h; ol[o] = lo;
        }
      } else {
        int d = n_g - 256;
        int bb = m_base >> 11;
        int tt = m_base & 2047;
        ushort4 ovh, ovl;
#pragma unroll
        for (int r = 0; r < 4; ++r){
          float v = acc[mf][nf][r];
          u16 h = f2bf(v);
          u16 lo = f2bf(v - bf2f(h));
          ((u16*)&ovh)[r] = h;
          ((u16*)&ovl)[r] = lo;
        }
        size_t o = (size_t)bb * (128 * 2048) + (size_t)d * 2048 + tt;
        *(ushort4*)&vth[o] = ovh;
        *(ushort4*)&vtl[o] = ovl;
      }
    }
}

// ---- kernel 3: causal flash attention, split-K across 4 waves per block ----
// Block = one 16-row q-tile; wave wv handles k-tiles wv, wv+4, ... with
// private online-softmax state; LDS merge at the end.
// S^T = K . Q^T (softmax rows lane-local), O^T = V^T . P^T.
// Tiles kt<ktmax are provably fully-unmasked (ktmax*64 <= q0+1 for all
// qt mod 4), so the causal mask is applied only on the last tile.
__global__ __launch_bounds__(256) void attn_kernel(
    const u16* __restrict__ qh, const u16* __restrict__ ql,
    const u16* __restrict__ kh, const u16* __restrict__ kl,
    const u16* __restrict__ vth, const u16* __restrict__ vtl,
    float* __restrict__ out){
  __shared__ float Opart[4][16][132];          // 33 KB, padded vs bank conflicts
  __shared__ float Mpart[4][16], Lpart[4][16];
  __shared__ u16 Ph[4][16 * 88], Pl[4][16 * 88]; // stride 88 (16B-aligned rows)
  int blk = blockIdx.x;                        // 512
  int b = blk & 3;                             // batch pinned to XCDs {b, b+4}
  int v_ = blk >> 2;                           // 0..127
  int qt = (v_ < 64) ? v_ : 191 - v_;          // CU-pair causal balance
  int q0 = qt * 16;
  int t = threadIdx.x;
  int lane = t & 63, wv = t >> 6;
  int c = lane & 15, g = lane >> 4;
  u16* ph = Ph[wv];
  u16* pl = Pl[wv];

  size_t qrow = ((size_t)b * 2048 + q0 + c) * 128;
  s16x8 qbh[4], qbl[4];
#pragma unroll
  for (int ks = 0; ks < 4; ++ks){
    qbh[ks] = *(const s16x8*)&qh[qrow + ks * 32 + g * 8];
    qbl[ks] = *(const s16x8*)&ql[qrow + ks * 32 + g * 8];
  }

  f32x4 accO[8] = {};
  float m = -INFINITY, lsum = 0.f;
  int ktmax = (q0 + 15) >> 6;

  for (int kt = wv; kt <= ktmax; kt += 4){
    // ---- S^T tile [64k x 16q] ----
    f32x4 s[4] = {};
#pragma unroll
    for (int kb = 0; kb < 4; ++kb){
      size_t krow = ((size_t)b * 2048 + kt * 64 + kb * 16 + c) * 128;
#pragma unroll
      for (int ks = 0; ks < 4; ++ks){
        s16x8 a_h = *(const s16x8*)&kh[krow + ks * 32 + g * 8];
        s16x8 a_l = *(const s16x8*)&kl[krow + ks * 32 + g * 8];
        s[kb] = mfma16(a_h, qbh[ks], s[kb]);
        s[kb] = mfma16(a_h, qbl[ks], s[kb]);
        s[kb] = mfma16(a_l, qbh[ks], s[kb]);
      }
    }
    if (kt == ktmax){
#pragma unroll
      for (int kb = 0; kb < 4; ++kb)
#pragma unroll
        for (int r = 0; r < 4; ++r){
          int kg = kt * 64 + kb * 16 + g * 4 + r;
          if (kg > q0 + c) s[kb][r] = -3.0e38f;
        }
    }
    // ---- online softmax (row = query = lane&15; 4 lanes per row) ----
    float pmax = s[0][0];
#pragma unroll
    for (int kb = 0; kb < 4; ++kb)
#pragma unroll
      for (int r = 0; r < 4; ++r) pmax = fmaxf(pmax, s[kb][r]);
    pmax = fmaxf(pmax, __shfl_xor(pmax, 16));
    pmax = fmaxf(pmax, __shfl_xor(pmax, 32));
    float mnew = fmaxf(m, pmax);
    float corr = exp2f((m - mnew) * LOG2E);
    float psum = 0.f;
#pragma unroll
    for (int kb = 0; kb < 4; ++kb){
      ushort4 wh_, wl_;
#pragma unroll
      for (int r = 0; r < 4; ++r){
        float p = exp2f((s[kb][r] - mnew) * LOG2E);
        psum += p;
        u16 h = f2bf(p);
        ((u16*)&wh_)[r] = h;
        ((u16*)&wl_)[r] = f2bf(p - bf2f(h));
      }
      *(ushort4*)&ph[c * 88 + kb * 16 + g * 4] = wh_;
      *(ushort4*)&pl[c * 88 + kb * 16 + g * 4] = wl_;
    }
    psum += __shfl_xor(psum, 16);
    psum += __shfl_xor(psum, 32);
    lsum = lsum * corr + psum;
    m = mnew;
#pragma unroll
    for (int db = 0; db < 8; ++db)
#pragma unroll
      for (int r = 0; r < 4; ++r) accO[db][r] *= corr;

    // intra-wave LDS bounce: C-layout P -> B-fragment layout (wave-private).
    // asm waitcnt + memory clobber = compiler reorder fence for the
    // cross-lane ds_write -> ds_read dependency.
    asm volatile("s_waitcnt lgkmcnt(0)" ::: "memory");
    s16x8 pbh[2], pbl[2];
#pragma unroll
    for (int ks2 = 0; ks2 < 2; ++ks2){
      pbh[ks2] = *(const s16x8*)&ph[c * 88 + ks2 * 32 + g * 8];
      pbl[ks2] = *(const s16x8*)&pl[c * 88 + ks2 * 32 + g * 8];
    }
    // ---- O^T += V^T . P^T ----
#pragma unroll
    for (int db = 0; db < 8; ++db){
      size_t vrow = ((size_t)b * 128 + db * 16 + c) * 2048 + (size_t)kt * 64;
#pragma unroll
      for (int ks2 = 0; ks2 < 2; ++ks2){
        s16x8 a_h = *(const s16x8*)&vth[vrow + ks2 * 32 + g * 8];
        s16x8 a_l = *(const s16x8*)&vtl[vrow + ks2 * 32 + g * 8];
        accO[db] = mfma16(a_h, pbh[ks2], accO[db]);
        accO[db] = mfma16(a_h, pbl[ks2], accO[db]);
        accO[db] = mfma16(a_l, pbh[ks2], accO[db]);
      }
    }
  }

  // ---- write per-wave partials ----
  if (g == 0){ Mpart[wv][c] = m; Lpart[wv][c] = lsum; }
#pragma unroll
  for (int db = 0; db < 8; ++db)
    *(f32x4*)&Opart[wv][c][db * 16 + g * 4] = accO[db];
  __syncthreads();

  // ---- merge 4 partials: thread t -> query q = t>>4, d-chunk dg = t&15 ----
  int q = t >> 4, dg = t & 15;
  float M = fmaxf(fmaxf(Mpart[0][q], Mpart[1][q]),
                  fmaxf(Mpart[2][q], Mpart[3][q]));
  float sc[4]; float L = 0.f;
#pragma unroll
  for (int w = 0; w < 4; ++w){
    sc[w] = exp2f((Mpart[w][q] - M) * LOG2E);
    L += Lpart[w][q] * sc[w];
  }
  float invL = 1.0f / L;
  float o[8] = {0,0,0,0,0,0,0,0};
#pragma unroll
  for (int w = 0; w < 4; ++w){
    float4 a = *(const float4*)&Opart[w][q][dg * 8];
    float4 bq = *(const float4*)&Opart[w][q][dg * 8 + 4];
    o[0] += sc[w] * a.x;  o[1] += sc[w] * a.y;
    o[2] += sc[w] * a.z;  o[3] += sc[w] * a.w;
    o[4] += sc[w] * bq.x; o[5] += sc[w] * bq.y;
    o[6] += sc[w] * bq.z; o[7] += sc[w] * bq.w;
  }
  size_t obase = ((size_t)b * 2048 + q0 + q) * 128 + dg * 8;
  float4 r0, r1;
  r0.x = o[0] * invL; r0.y = o[1] * invL; r0.z = o[2] * invL; r0.w = o[3] * invL;
  r1.x = o[4] * invL; r1.y = o[5] * invL; r1.z = o[6] * invL; r1.w = o[7] * invL;
  *(float4*)&out[obase] = r0;
  *(float4*)&out[obase + 4] = r1;
}

extern "C" void kernel_launch(void* const* d_in, const int* in_sizes, int n_in,
                              void* d_out, int out_size, void* d_ws, size_t ws_size,
                              hipStream_t stream){
  (void)in_sizes; (void)n_in; (void)out_size;
  const float* x  = (const float*)d_in[0];
  const float* Wq = (const float*)d_in[1];
  const float* Wk = (const float*)d_in[2];
  const float* Wv = (const float*)d_in[3];
  float* out = (float*)d_out;

  char* ws = (char*)d_ws;
  size_t off = 0;
  auto alloc = [&](size_t bytes) -> void* {
    void* p = ws + off;
    off += (bytes + 255) & ~(size_t)255;
    return p;
  };
  u16* xh  = (u16*)alloc((size_t)8192 * 1024 * 2);
  u16* xl  = (u16*)alloc((size_t)8192 * 1024 * 2);
  u16* wth = (u16*)alloc((size_t)384 * 1024 * 2);
  u16* wtl = (u16*)alloc((size_t)384 * 1024 * 2);
  u16* qh  = (u16*)alloc((size_t)8192 * 128 * 2);
  u16* ql  = (u16*)alloc((size_t)8192 * 128 * 2);
  u16* kh  = (u16*)alloc((size_t)8192 * 128 * 2);
  u16* kl  = (u16*)alloc((size_t)8192 * 128 * 2);
  u16* vth = (u16*)alloc((size_t)8192 * 128 * 2);
  u16* vtl = (u16*)alloc((size_t)8192 * 128 * 2);

  // Safety: never write past the harness workspace. If it's too small,
  // launch nothing -> clean validation failure instead of an OOB crash.
  // (Depends only on the constant ws_size, so identical work every call.)
  if (ws_size < off) return;

  prep_kernel<<<4192, 256, 0, stream>>>(x, Wq, Wk, Wv, xh, xl, wth, wtl);
  qkv_gemm_kernel<<<768, 256, 0, stream>>>(xh, xl, wth, wtl,
                                           qh, ql, kh, kl, vth, vtl);
  attn_kernel<<<512, 256, 0, stream>>>(qh, ql, kh, kl, vth, vtl, out);
}